// Round 7
// baseline (185.732 us; speedup 1.0000x reference)
//
#include <hip/hip_runtime.h>
#include <hip/hip_bf16.h>

// Problem constants (ResNet-50 CBP head)
#define BATCH 8
#define CH    2048
#define LSP   784          // H*W = 28*28
#define KPAD  832          // pad K to 13*64: full-128B-line k-stages
#define KSTAGE 13          // k-stages of BK=64 (2 MFMA k-substeps each)
#define DDIM  8192         // count-sketch dim (power of 2)
#define NCLS  200
#define NTILE 16           // 2048/128 tiles per dim
#define NPAIR 136          // NTILE*(NTILE+1)/2 symmetric tile pairs
#define NSLOT 68           // fallback: part slots per batch (2 blocks/slot)
#define FXSCALE 8192.0f    // fixed-point scale 2^13 (split as 64*128 into meta)
#define FXINV   (1.0f/8192.0f)

typedef _Float16 f16x8 __attribute__((ext_vector_type(8)));
typedef _Float16 f16x4 __attribute__((ext_vector_type(4)));
typedef float    f32x4 __attribute__((ext_vector_type(4)));

#define FATOMIC(p, v) unsafeAtomicAdd((p), (v))

// ---------------------------------------------------------------------------
// Kernel 1: convert x (fp32 [B,C,784]) to fp16 [B,C,KPAD] (zero-pad K).
// Also: zero norm, bias-seed logits, build the packed scatter-meta table
// metaG[c] = (s1[c]*64, h1[c], s2[c]*128, h2[c]) (2^13 fixed-point scale
// rides the s1*s2 product), and -- ONLY in atomic-fallback mode -- zero part.
// ---------------------------------------------------------------------------
__global__ __launch_bounds__(256) void split_kernel(
    const float* __restrict__ x,
    _Float16* __restrict__ xh,
    float* __restrict__ part, float* __restrict__ norm,
    const float* __restrict__ s1, const int* __restrict__ h1,
    const float* __restrict__ s2, const int* __restrict__ h2,
    float4* __restrict__ metaG,
    const float* __restrict__ bc, float* __restrict__ out,
    int exclusive)
{
    int idx = blockIdx.x * 256 + threadIdx.x;          // vec4 index
    if (!exclusive && idx < NSLOT * BATCH * DDIM / 4)  // zero part (fallback)
        *(float4*)&part[idx * 4] = make_float4(0.f, 0.f, 0.f, 0.f);
    if (idx < CH)
        metaG[idx] = make_float4(s1[idx] * 64.0f, __int_as_float(h1[idx]),
                                 s2[idx] * 128.0f, __int_as_float(h2[idx]));
    if (idx < BATCH) norm[idx] = 0.0f;
    if (idx < BATCH * NCLS) out[idx] = bc[idx % NCLS]; // bias-seed logits
    if (idx >= BATCH * CH * KPAD / 4) return;
    int v  = idx * 4;
    int bc_ = v / KPAD;
    int l  = v - bc_ * KPAD;                           // multiple of 4
    float4 xv = make_float4(0.f, 0.f, 0.f, 0.f);
    if (l < LSP)                                       // LSP%4==0: uniform per vec
        xv = *(const float4*)&x[(size_t)bc_ * LSP + l];
    f16x4 hv;
    hv[0] = (_Float16)xv.x; hv[1] = (_Float16)xv.y;
    hv[2] = (_Float16)xv.z; hv[3] = (_Float16)xv.w;
    *(f16x4*)&xh[v] = hv;
}

// ---------------------------------------------------------------------------
// Kernel 2: symmetric Gram tile + count-sketch scatter (int32 LDS histogram).
// R7 theory: R6's remaining 2.5k cyc/stage (vs ~500 of work) is the exposed
// global->LDS round trip: global_load_lds + __syncthreads drains vmcnt(0)
// every stage (the m97-structure stall). Fix: REG-STAGED PREFETCH (T14) --
// load stage s+1 into VGPRs while stage s computes from LDS. Per stage:
//   s_barrier ; ds_write(regs s) ; issue loads(s+1) ; lgkmcnt(0)+s_barrier ;
//   ds_read + 32 MFMA
// Raw s_barrier (not __syncthreads) so the in-flight prefetch loads are NOT
// drained at the barrier; the only vmcnt wait is the compiler's data-dep
// wait before ds_write -- and those loads had a full stage to land.
// Swizzle: write chunk c^= row&7 (ds_write side), read with same XOR --
// both-sides involution (rule 21 applies only to global_load_lds).
// Scatter: banked ds_add_u32 (R4). Flush: exclusive slot plain stores (R5).
// LDS 64 KB (smA 16 + smB 16 + bins 32) -> 2 blocks/CU (= 2 waves/SIMD,
// 256-VGPR budget: +32 staging regs is free).
// grid = 1088: batch = id&7 (one batch per XCD), pair = id>>3.
// ---------------------------------------------------------------------------
__device__ __forceinline__ void loadregs(
    const _Float16* __restrict__ src,   // xh + (b*CH + tile*128)*KPAD
    int wv, int lane, int s, f16x8 r[4])
{
    const int rowi = lane >> 3;                 // 0..7 row within 8-row group
    const int gc   = lane & 7;                  // linear 8-half chunk
    const _Float16* g0 = src + (size_t)(wv * 32 + rowi) * KPAD + s * 64 + gc * 8;
#pragma unroll
    for (int q = 0; q < 4; ++q)
        r[q] = *(const f16x8*)(g0 + (size_t)(q * 8) * KPAD);
}

__device__ __forceinline__ void writelds(
    unsigned short* lds, int wv, int lane, const f16x8 r[4])
{
    const int rowi = lane >> 3;
    const int c2   = (lane & 7) ^ rowi;         // swizzled chunk (row&7 == rowi)
    unsigned short* d0 = lds + (wv * 32 + rowi) * 64 + c2 * 8;
#pragma unroll
    for (int q = 0; q < 4; ++q)
        *(f16x8*)(d0 + q * 8 * 64) = r[q];
}

__global__ __launch_bounds__(256, 2) void gram_scatter_kernel(
    const _Float16* __restrict__ xh,
    const float4* __restrict__ metaG,
    float* __restrict__ part,
    int exclusive)
{
    __shared__ __align__(16) unsigned short smA[128 * 64];   // 16 KB
    __shared__ __align__(16) unsigned short smB[128 * 64];   // 16 KB
    __shared__ __align__(16) int bins[DDIM];                 // 32 KB

    const int tid  = threadIdx.x;
    const int lane = tid & 63;
    const int wv   = tid >> 6;
    const int b    = blockIdx.x & 7;       // batch in low bits -> one batch/XCD
    const int pidx = blockIdx.x >> 3;      // triangular pair index

    for (int i = tid; i < DDIM; i += 256) bins[i] = 0;

    // Triangular decode: pidx in [0,136) -> (tM, tN), tM <= tN, row-major
    int tM = 0, tN = 0;
    {
        int i = pidx;
#pragma unroll 1
        for (int t = 0; t < NTILE; ++t) {
            int cnt = NTILE - t;
            if (i < cnt) { tM = t; tN = t + i; break; }
            i -= cnt;
        }
    }
    const bool diag = (tM == tN);

    const int wrow = (wv >> 1) * 64;    // wave's 64x64 subtile origin
    const int wcol = (wv & 1) * 64;
    const int rsel = lane & 15;
    const int khi  = lane >> 4;         // k 8-half group within a k-substep

    const _Float16* srcA = xh + ((size_t)b * CH + (size_t)tM * 128) * KPAD;
    const _Float16* srcB = xh + ((size_t)b * CH + (size_t)tN * 128) * KPAD;
    const unsigned short* fragB = diag ? smA : smB;

    f32x4 acc[4][4];
    const f32x4 zv = {0.0f, 0.0f, 0.0f, 0.0f};
#pragma unroll
    for (int mi = 0; mi < 4; ++mi)
#pragma unroll
        for (int ni = 0; ni < 4; ++ni) acc[mi][ni] = zv;

    // Prologue: prefetch stage 0 into registers.
    f16x8 ra[4], rb[4];
    loadregs(srcA, wv, lane, 0, ra);
    if (!diag) loadregs(srcB, wv, lane, 0, rb);

#pragma unroll 1
    for (int s = 0; s < KSTAGE; ++s) {
        // Barrier 1: all waves done reading stage s-1 from LDS (s=0: orders
        // nothing critical -- bins init visibility handled by barrier 2).
        __builtin_amdgcn_s_barrier();
        // ds_write stage s (compiler inserts the vmcnt wait for ra/rb here;
        // the loads were issued one full stage ago -> usually landed).
        writelds(smA, wv, lane, ra);
        if (!diag) writelds(smB, wv, lane, rb);
        // Prefetch stage s+1 (stays in flight across the barrier below).
        if (s + 1 < KSTAGE) {
            loadregs(srcA, wv, lane, s + 1, ra);
            if (!diag) loadregs(srcB, wv, lane, s + 1, rb);
        }
        // Our ds_writes (and, at s=0, the bins-init stores) complete...
        asm volatile("s_waitcnt lgkmcnt(0)" ::: "memory");
        __builtin_amdgcn_sched_barrier(0);
        __builtin_amdgcn_s_barrier();   // ...and are visible to all waves.
#pragma unroll
        for (int t = 0; t < 2; ++t) {
            // swizzled chunk: global chunk (t*4+khi) lives at LDS chunk
            // (t*4+khi)^(row&7); row&7 == rsel&7 for all fragments here.
            const int co = ((((t << 2) + khi) ^ (rsel & 7)) << 3);
            f16x8 ah[4], bh[4];
#pragma unroll
            for (int i = 0; i < 4; ++i) {
                ah[i] = *(const f16x8*)&smA[(wrow + i * 16 + rsel) * 64 + co];
                bh[i] = *(const f16x8*)&fragB[(wcol + i * 16 + rsel) * 64 + co];
            }
#pragma unroll
            for (int mi = 0; mi < 4; ++mi)
#pragma unroll
                for (int ni = 0; ni < 4; ++ni)
                    acc[mi][ni] = __builtin_amdgcn_mfma_f32_16x16x32_f16(
                        ah[mi], bh[ni], acc[mi][ni], 0, 0, 0);
        }
    }

    // Column meta: one packed float4 per c2 (VMEM, L2-hot). s-values carry
    // the fixed-point scale (s1*64, s2*128).
    const int c2b = tN * 128 + wcol + rsel;
    int   h1c[4], h2c[4]; float s1c[4], s2c[4];
#pragma unroll
    for (int ni = 0; ni < 4; ++ni) {
        float4 cm = metaG[c2b + ni * 16];
        s1c[ni] = cm.x; h1c[ni] = __float_as_int(cm.y);
        s2c[ni] = cm.z; h2c[ni] = __float_as_int(cm.w);
    }

    // Scatter the 128x128 Gram tile into the LDS int histogram.
    // C/D layout (m89-verified): col = lane&15, row = (lane>>4)*4 + reg
    // Row meta also via VMEM -> zero lgkmcnt-ordered ops between ds_adds.
    // (No barrier needed before scatter: ds_adds touch bins only, disjoint
    //  from smA/smB; bins-init visibility was established at stage 0.)
    const int rowbase = tM * 128 + wrow + (khi << 2);
#pragma unroll
    for (int mi = 0; mi < 4; ++mi) {
        float4 rm[4];
#pragma unroll
        for (int r = 0; r < 4; ++r) rm[r] = metaG[rowbase + mi * 16 + r];
#pragma unroll
        for (int r = 0; r < 4; ++r) {
            const float s1r = rm[r].x, s2r = rm[r].z;
            const int h1r = __float_as_int(rm[r].y);
            const int h2r = __float_as_int(rm[r].w);
#pragma unroll
            for (int ni = 0; ni < 4; ++ni) {
                float g = acc[mi][ni][r];
                atomicAdd(&bins[(h1r + h2c[ni]) & (DDIM - 1)],
                          (int)(s1r * s2c[ni] * g));
                if (!diag)
                    atomicAdd(&bins[(h1c[ni] + h2r) & (DDIM - 1)],
                              (int)(s1c[ni] * s2r * g));
            }
        }
    }

    __syncthreads();   // all scatters into bins complete

    if (exclusive) {
        // Exclusive slot: plain coalesced float4 stores through L2.
        float* pbase = part + ((size_t)(pidx * BATCH + b) * DDIM);
#pragma unroll 4
        for (int i = tid; i < DDIM / 4; i += 256) {
            int4 v = *(const int4*)&bins[i * 4];
            float4 f = make_float4((float)v.x * FXINV, (float)v.y * FXINV,
                                   (float)v.z * FXINV, (float)v.w * FXINV);
            *(float4*)&pbase[i * 4] = f;
        }
    } else {
        // Fallback: 68 shared slots, fp32 global atomics, rotated start.
        float* pbase = part + ((size_t)((pidx % NSLOT) * BATCH + b) * DDIM);
        const int rot = (blockIdx.x & 31) << 8;
        for (int i = tid; i < DDIM; i += 256) {
            int j = (i + rot) & (DDIM - 1);
            int v = bins[j];
            if (v != 0) FATOMIC(&pbase[j], (float)v * FXINV);
        }
    }
}

// ---------------------------------------------------------------------------
// Kernel 3: y[b,d] = sum over nslots part slots; norm[b] += sum|y|.
// R7: grid 256 (was 64) -- one scalar float per thread, all CUs active.
// The old 64-block version ran at single-block-per-CU bandwidth (~25-30us
// for 35.7 MB); 4x the blocks ~ 4x the streaming BW.
// batch = blockIdx&7 keeps reads on the XCD whose L2 holds that batch's part.
// NOTE: overwrites y, whose first 32 KB doubled as metaG for the (already
// finished) gram kernel -- intentional workspace reuse.
// ---------------------------------------------------------------------------
__global__ __launch_bounds__(256) void reduce_kernel(
    const float* __restrict__ part, float* __restrict__ y,
    float* __restrict__ norm, int nslots)
{
    const int tid = threadIdx.x;
    const int b   = blockIdx.x & 7;
    const int d0  = (blockIdx.x >> 3) * 256 + tid;     // scalar float index
    float s = 0.0f;
#pragma unroll 8
    for (int p = 0; p < nslots; ++p)
        s += part[((size_t)p * BATCH + b) * DDIM + d0];
    y[(size_t)b * DDIM + d0] = s;
    float ab = fabsf(s);
    __shared__ float red[256];
    red[tid] = ab;
    __syncthreads();
    for (int st = 128; st > 0; st >>= 1) {
        if (tid < st) red[tid] += red[tid + st];
        __syncthreads();
    }
    if (tid == 0) FATOMIC(&norm[b], red[0]);   // sum|y| == sum feat_unnorm^2
}

// ---------------------------------------------------------------------------
// Kernel 4: fused signed-sqrt + L2-normalize + classifier GEMV.
// grid 64: block j owns d in [128j, 128j+128) for all batches.
// ---------------------------------------------------------------------------
__global__ __launch_bounds__(256) void logit_kernel(
    const float* __restrict__ y, const float* __restrict__ norm,
    const float* __restrict__ W, float* __restrict__ out)
{
    const int j = blockIdx.x;
    const int tid = threadIdx.x;
    __shared__ float fs[BATCH][128];                   // 4 KB
    for (int i = tid; i < BATCH * 128; i += 256) {
        int bb = i >> 7, dd = i & 127;
        float v = y[(size_t)bb * DDIM + j * 128 + dd];
        float inv = 1.0f / fmaxf(sqrtf(norm[bb]), 1e-12f);
        float f = copysignf(sqrtf(fabsf(v)), v) * inv;
        fs[bb][dd] = f;
        out[BATCH * NCLS + (size_t)bb * DDIM + j * 128 + dd] = f;
    }
    __syncthreads();
    if (tid < NCLS) {
        float a[BATCH];
#pragma unroll
        for (int bb = 0; bb < BATCH; ++bb) a[bb] = 0.0f;
        for (int dd = 0; dd < 128; ++dd) {
            float w = W[(size_t)(j * 128 + dd) * NCLS + tid];
#pragma unroll
            for (int bb = 0; bb < BATCH; ++bb) a[bb] += fs[bb][dd] * w;
        }
#pragma unroll
        for (int bb = 0; bb < BATCH; ++bb)
            FATOMIC(&out[bb * NCLS + tid], a[bb]);
    }
}

// ---------------------------------------------------------------------------
extern "C" void kernel_launch(void* const* d_in, const int* in_sizes, int n_in,
                              void* d_out, int out_size, void* d_ws, size_t ws_size,
                              hipStream_t stream)
{
    const float* x  = (const float*)d_in[0];
    const float* s1 = (const float*)d_in[1];
    const float* s2 = (const float*)d_in[2];
    const float* W  = (const float*)d_in[3];
    const float* bc = (const float*)d_in[4];
    const int*   h1 = (const int*)d_in[5];
    const int*   h2 = (const int*)d_in[6];
    float* out = (float*)d_out;

    const size_t ybytes  = (size_t)BATCH * DDIM * sizeof(float);
    const size_t xhbytes = (size_t)BATCH * CH * KPAD * sizeof(_Float16);

    // Prefer exclusive mode: part = 136 slots (34 MB), plain-store flush.
    // Fallback (ws too small): 68 shared slots + atomic flush (R4 scheme).
    size_t partbytes = (size_t)NPAIR * BATCH * DDIM * sizeof(float);
    int exclusive = (ws_size >= partbytes + ybytes + 128 + xhbytes);
    if (!exclusive)
        partbytes = (size_t)NSLOT * BATCH * DDIM * sizeof(float);
    const int nslots = exclusive ? NPAIR : NSLOT;

    // ws layout: part | y (first 32KB doubles as metaG until reduce) | norm | xh
    char* ws = (char*)d_ws;
    float* part = (float*)ws;
    float* y    = (float*)(ws + partbytes);
    float4* metaG = (float4*)(ws + partbytes);         // overlay on y region
    float* norm = (float*)(ws + partbytes + ybytes);
    _Float16* xh = (_Float16*)(ws + partbytes + ybytes + 128);

    split_kernel<<<(BATCH * CH * KPAD / 4 + 255) / 256, 256, 0, stream>>>(
        x, xh, part, norm, s1, h1, s2, h2, metaG, bc, out, exclusive);

    gram_scatter_kernel<<<NPAIR * BATCH, 256, 0, stream>>>(
        xh, metaG, part, exclusive);

    reduce_kernel<<<256, 256, 0, stream>>>(part, y, norm, nslots);

    logit_kernel<<<64, 256, 0, stream>>>(y, norm, W, out);
}